// Round 4
// baseline (218.715 us; speedup 1.0000x reference)
//
#include <hip/hip_runtime.h>

#define N0 4096
#define N1 2048
#define N2 1024

// ============ restrict: fc = restrict(f + 0.2*L(f)) ============
// coarse 32x32 outputs/block, fine 64x64 tile, 256 threads
__global__ __launch_bounds__(256) void k_res_restrict(const float* __restrict__ f,
                                                      float* __restrict__ fc,
                                                      int n, int nc) {
    __shared__ __align__(16) float sf[66][76];
    const int tid = threadIdx.x;
    const int A0 = blockIdx.y * 32, B0 = blockIdx.x * 32;
    const int fy0 = 2 * A0 - 1, fx0 = 2 * B0 - 4;       // staged origin
    const bool edge = (blockIdx.x == 0) | (blockIdx.y == 0) |
                      (blockIdx.x == gridDim.x - 1) | (blockIdx.y == gridDim.y - 1);
    const int tx = tid & 7, ty = tid >> 3;               // 8 x 32

    if (!edge) {
        for (int idx = tid; idx < 66 * 18; idx += 256) {
            int r = idx / 18, c4 = idx - r * 18;
            *(float4*)&sf[r][4 * c4] =
                *(const float4*)(f + (size_t)(fy0 + r) * n + (fx0 + 4 * c4));
        }
        __syncthreads();
        float w[4][16];
        #pragma unroll
        for (int rr = 0; rr < 4; ++rr) {
            #pragma unroll
            for (int k = 0; k < 4; ++k)
                *(float4*)&w[rr][4 * k] = *(float4*)&sf[2 * ty + rr][8 * tx + 4 * k];
        }
        float4 outv;
        #pragma unroll
        for (int j = 0; j < 4; ++j) {
            const int e = 2 * j + 3;  // window col of fine 2b-1
            float q = w[1][e+1] + w[1][e+2] + w[2][e+1] + w[2][e+2];
            float ring = w[0][e+1] + w[0][e+2] + w[3][e+1] + w[3][e+2]
                       + w[1][e]   + w[2][e]   + w[1][e+3] + w[2][e+3];
            (&outv.x)[j] = 0.15f * q + 0.05f * ring;
        }
        *(float4*)(fc + (size_t)(A0 + ty) * nc + (B0 + 4 * tx)) = outv;
    } else {
        for (int idx = tid; idx < 66 * 72; idx += 256) {
            int r = idx / 72, c = idx - r * 72;
            int gy = fy0 + r, gx = fx0 + c;
            float v = 0.0f;
            if ((unsigned)gy < (unsigned)n && (unsigned)gx < (unsigned)n)
                v = f[(size_t)gy * n + gx];
            sf[r][c] = v;
        }
        __syncthreads();
        auto r_at = [&](int lr, int lc, int gy, int gx) -> float {
            float c = sf[lr][lc];
            if (gy == 0 || gy == n - 1 || gx == 0 || gx == n - 1) return c;
            return c + 0.2f * (sf[lr-1][lc] + sf[lr+1][lc] +
                               sf[lr][lc-1] + sf[lr][lc+1] - 4.0f * c);
        };
        #pragma unroll
        for (int j = 0; j < 4; ++j) {
            int a = A0 + ty, b = B0 + 4 * tx + j;
            int lr = 2 * ty + 1, lc = 8 * tx + 2 * j + 4;
            int gy = 2 * a, gx = 2 * b;
            float v = r_at(lr,   lc,   gy,   gx) + r_at(lr,   lc+1, gy,   gx+1)
                    + r_at(lr+1, lc,   gy+1, gx) + r_at(lr+1, lc+1, gy+1, gx+1);
            fc[(size_t)a * nc + b] = 0.25f * v;
        }
    }
}

// ====== fused: u = jacobi(cf*f + cs*prolong(uc), f), optional residual ======
// 64x64 outputs/block, 256 threads.
// sf: f, row = gy-(by0-2), col = gx-(bx0-4)    (rows 0..67, cols 0..71)
// sv: v, row = gy-(by0-2), col = gx-(bx0-2)    (rows 0..67, cols 0..67)
// su: u, row = gy-(by0-1), col = gx-(bx0-2)    (rows 0..65, cols 0..67)
// suc: cs*uc, row = a-(by0/2-2), col = b-(bx0/2-4)
template <bool RESID>
__global__ __launch_bounds__(256) void k_correct_smooth(
        const float* __restrict__ f, const float* __restrict__ uc,
        float* __restrict__ u, int n, int m, float cf, float cs,
        double* __restrict__ pT, double* __restrict__ pF) {
    __shared__ __align__(16) float sf[68][76];
    __shared__ __align__(16) float sv[68][76];
    __shared__ __align__(16) float su[66][76];
    __shared__ __align__(16) float suc[36][44];
    const int tid = threadIdx.x;
    const int by0 = blockIdx.y * 64, bx0 = blockIdx.x * 64;
    const bool edge = (blockIdx.x == 0) | (blockIdx.y == 0) |
                      (blockIdx.x == gridDim.x - 1) | (blockIdx.y == gridDim.y - 1);

    if (!edge) {
        // ---- A: stage f (68x18 float4) and cs*uc (36x10 float4) ----
        for (int idx = tid; idx < 68 * 18; idx += 256) {
            int r = idx / 18, c4 = idx - r * 18;
            *(float4*)&sf[r][4 * c4] =
                *(const float4*)(f + (size_t)(by0 - 2 + r) * n + (bx0 - 4 + 4 * c4));
        }
        for (int idx = tid; idx < 360; idx += 256) {
            int r = idx / 10, c4 = idx - r * 10;
            float4 v = *(const float4*)(uc + (size_t)(by0/2 - 2 + r) * m + (bx0/2 - 4 + 4 * c4));
            v.x *= cs; v.y *= cs; v.z *= cs; v.w *= cs;
            *(float4*)&suc[r][4 * c4] = v;
        }
        __syncthreads();
        // ---- B: v on 68x68 via 34x34 2x2 quads ----
        for (int idx = tid; idx < 1156; idx += 256) {
            int qr = idx / 34, qc = idx - qr * 34;
            float s00 = suc[qr  ][qc+2], s01 = suc[qr  ][qc+3], s02 = suc[qr  ][qc+4];
            float s10 = suc[qr+1][qc+2], s11 = suc[qr+1][qc+3], s12 = suc[qr+1][qc+4];
            float s20 = suc[qr+2][qc+2], s21 = suc[qr+2][qc+3], s22 = suc[qr+2][qc+4];
            float h0a = 0.5f*s00 + 1.5f*s01, h0b = 1.5f*s01 + 0.5f*s02;
            float h1a = 0.5f*s10 + 1.5f*s11, h1b = 1.5f*s11 + 0.5f*s12;
            float h2a = 0.5f*s20 + 1.5f*s21, h2b = 1.5f*s21 + 0.5f*s22;
            float2 ft = *(float2*)&sf[2*qr  ][2*qc + 2];
            float2 fb = *(float2*)&sf[2*qr+1][2*qc + 2];
            float2 vt, vb;
            vt.x = cf * ft.x + 0.5f*h0a + 1.5f*h1a;
            vt.y = cf * ft.y + 0.5f*h0b + 1.5f*h1b;
            vb.x = cf * fb.x + 1.5f*h1a + 0.5f*h2a;
            vb.y = cf * fb.y + 1.5f*h1b + 0.5f*h2b;
            *(float2*)&sv[2*qr  ][2*qc] = vt;
            *(float2*)&sv[2*qr+1][2*qc] = vb;
        }
        __syncthreads();
        // ---- C: u on 66 rows x 17 strips of 4 (aligned b128) ----
        for (int idx = tid; idx < 1122; idx += 256) {
            int r = idx / 17, s = idx - r * 17;
            float4 top = *(float4*)&sv[r    ][4 * s];
            float4 mid = *(float4*)&sv[r + 1][4 * s];
            float4 bot = *(float4*)&sv[r + 2][4 * s];
            float lft = sv[r + 1][4 * s - 1];   // garbage for s=0 (col unused)
            float rgt = sv[r + 1][4 * s + 4];   // garbage for s=16 (col unused)
            float2 fa = *(float2*)&sf[r + 1][4 * s + 2];
            float2 fb = *(float2*)&sf[r + 1][4 * s + 4];
            float4 uu;
            uu.x = mid.x + cf * fa.x + 0.2f * (top.x + bot.x + lft   + mid.y - 4.0f * mid.x);
            uu.y = mid.y + cf * fa.y + 0.2f * (top.y + bot.y + mid.x + mid.z - 4.0f * mid.y);
            uu.z = mid.z + cf * fb.x + 0.2f * (top.z + bot.z + mid.y + mid.w - 4.0f * mid.z);
            uu.w = mid.w + cf * fb.y + 0.2f * (top.w + bot.w + mid.z + rgt   - 4.0f * mid.w);
            *(float4*)&su[r][4 * s] = uu;
        }
        __syncthreads();
    } else {
        // ---- guarded slow path ----
        for (int idx = tid; idx < 68 * 72; idx += 256) {
            int r = idx / 72, c = idx - r * 72;
            int gy = by0 - 2 + r, gx = bx0 - 4 + c;
            float fv = 0.0f;
            if ((unsigned)gy < (unsigned)n && (unsigned)gx < (unsigned)n)
                fv = f[(size_t)gy * n + gx];
            sf[r][c] = fv;
        }
        __syncthreads();
        for (int idx = tid; idx < 68 * 68; idx += 256) {
            int r = idx / 68, c = idx - r * 68;
            int gy = by0 - 2 + r, gx = bx0 - 2 + c;
            float vv = 0.0f;
            if ((unsigned)gy < (unsigned)n && (unsigned)gx < (unsigned)n) {
                vv = cf * sf[r][c + 2];
                if (gy > 0 && gy < n - 1 && gx > 0 && gx < n - 1) {
                    int a0, a1, b0, b1; float wr0, wr1, wc0, wc1;
                    if (gy & 1) { a0 = gy >> 1; a1 = a0 + 1; wr0 = 1.5f; wr1 = 0.5f; }
                    else        { a1 = gy >> 1; a0 = a1 - 1; wr0 = 0.5f; wr1 = 1.5f; }
                    if (gx & 1) { b0 = gx >> 1; b1 = b0 + 1; wc0 = 1.5f; wc1 = 0.5f; }
                    else        { b1 = gx >> 1; b0 = b1 - 1; wc0 = 0.5f; wc1 = 1.5f; }
                    float p = wr0 * (wc0 * uc[(size_t)a0*m + b0] + wc1 * uc[(size_t)a0*m + b1])
                            + wr1 * (wc0 * uc[(size_t)a1*m + b0] + wc1 * uc[(size_t)a1*m + b1]);
                    vv += cs * p;
                }
            }
            sv[r][c] = vv;
        }
        __syncthreads();
        for (int idx = tid; idx < 66 * 68; idx += 256) {
            int r = idx / 68, c = idx - r * 68;
            int gy = by0 - 1 + r, gx = bx0 - 2 + c;
            float uu = 0.0f;
            if ((unsigned)gy < (unsigned)n && (unsigned)gx < (unsigned)n) {
                float vcv = sv[r + 1][c];
                uu = vcv + cf * sf[r + 1][c + 2];
                if (gy > 0 && gy < n - 1 && gx > 0 && gx < n - 1)
                    uu += 0.2f * (sv[r][c] + sv[r + 2][c] +
                                  sv[r + 1][c - 1] + sv[r + 1][c + 1] - 4.0f * vcv);
            }
            su[r][c] = uu;
        }
        __syncthreads();
    }

    // ---- D: write u (float4); fused residual partials ----
    const int tx = tid & 15, ty = tid >> 4;
    float accT = 0.0f, accF = 0.0f;
    const float n2 = (float)n * (float)n;
    #pragma unroll
    for (int k = 0; k < 4; ++k) {
        const int gy = by0 + 4 * ty + k;
        const int ur = 4 * ty + k + 1;
        const int c0 = 4 * tx + 2;
        float2 m0 = *(float2*)&su[ur][c0];
        float2 m1 = *(float2*)&su[ur][c0 + 2];
        float4 uu = make_float4(m0.x, m0.y, m1.x, m1.y);
        *(float4*)(u + (size_t)gy * n + (bx0 + 4 * tx)) = uu;
        if (RESID) {
            float2 t0 = *(float2*)&su[ur - 1][c0], t1 = *(float2*)&su[ur - 1][c0 + 2];
            float2 b0 = *(float2*)&su[ur + 1][c0], b1 = *(float2*)&su[ur + 1][c0 + 2];
            float2 l2 = *(float2*)&su[ur][c0 - 2];
            float2 r2 = *(float2*)&su[ur][c0 + 4];
            float4 fv = *(float4*)&sf[4 * ty + k + 2][4 * tx + 4];
            float lap0 = t0.x + b0.x + l2.y + m0.y - 4.0f * m0.x;
            float lap1 = t0.y + b0.y + m0.x + m1.x - 4.0f * m0.y;
            float lap2 = t1.x + b1.x + m0.y + m1.y - 4.0f * m1.x;
            float lap3 = t1.y + b1.y + m1.x + r2.x - 4.0f * m1.y;
            float r0 = fabsf(fv.x - n2 * lap0);
            float r1 = fabsf(fv.y - n2 * lap1);
            float r2v = fabsf(fv.z - n2 * lap2);
            float r3 = fabsf(fv.w - n2 * lap3);
            if (edge) {
                bool yb = (gy == 0) || (gy == n - 1);
                int gx0 = bx0 + 4 * tx;
                if (yb || gx0     == 0 || gx0     == n - 1) r0 = fabsf(fv.x);
                if (yb || gx0 + 1 == 0 || gx0 + 1 == n - 1) r1 = fabsf(fv.y);
                if (yb || gx0 + 2 == 0 || gx0 + 2 == n - 1) r2v = fabsf(fv.z);
                if (yb || gx0 + 3 == 0 || gx0 + 3 == n - 1) r3 = fabsf(fv.w);
            }
            accT += r0 + r1 + r2v + r3;
            accF += fabsf(fv.x) + fabsf(fv.y) + fabsf(fv.z) + fabsf(fv.w);
        }
    }
    if (RESID) {
        double* sT = (double*)&suc[0][0];
        double* sF = sT + 256;
        sT[tid] = (double)accT; sF[tid] = (double)accF;
        __syncthreads();
        for (int s = 128; s > 0; s >>= 1) {
            if (tid < s) { sT[tid] += sT[tid + s]; sF[tid] += sF[tid + s]; }
            __syncthreads();
        }
        if (tid == 0) {
            int bid = blockIdx.y * gridDim.x + blockIdx.x;
            pT[bid] = sT[0];
            pF[bid] = sF[0];
        }
    }
}

__global__ void k_final(const double* __restrict__ pT, const double* __restrict__ pF,
                        int nb, float* __restrict__ out_res) {
    __shared__ double sT[256], sF[256];
    double tT = 0.0, tF = 0.0;
    for (int i = threadIdx.x; i < nb; i += 256) { tT += pT[i]; tF += pF[i]; }
    sT[threadIdx.x] = tT; sF[threadIdx.x] = tF;
    __syncthreads();
    for (int s = 128; s > 0; s >>= 1) {
        if (threadIdx.x < s) { sT[threadIdx.x] += sT[threadIdx.x + s]; sF[threadIdx.x] += sF[threadIdx.x + s]; }
        __syncthreads();
    }
    if (threadIdx.x == 0) *out_res = (float)(sT[0] / sF[0]);
}

extern "C" void kernel_launch(void* const* d_in, const int* in_sizes, int n_in,
                              void* d_out, int out_size, void* d_ws, size_t ws_size,
                              hipStream_t stream) {
    const float* f0 = (const float*)d_in[0];
    float* u0  = (float*)d_out;
    float* res = u0 + (size_t)N0 * N0;

    char* ws = (char*)d_ws;
    float* f1 = (float*)ws;                                            // N1*N1
    float* u1 = (float*)(ws + (size_t)N1 * N1 * 4);                    // N1*N1
    float* f2 = (float*)(ws + (size_t)2 * N1 * N1 * 4);                // N2*N2
    double* pT = (double*)(ws + (size_t)2 * N1 * N1 * 4 + (size_t)N2 * N2 * 4);
    const int NB = (N0 / 64) * (N0 / 64);                              // 4096
    double* pF = pT + NB;

    const float c0 = -0.2f / ((float)N0 * (float)N0);
    const float c1 = -0.2f / ((float)N1 * (float)N1);
    const float c2 = -0.2f / ((float)N2 * (float)N2);

    k_res_restrict<<<dim3(N1 / 32, N1 / 32), 256, 0, stream>>>(f0, f1, N0, N1);
    k_res_restrict<<<dim3(N2 / 32, N2 / 32), 256, 0, stream>>>(f1, f2, N1, N2);
    k_correct_smooth<false><<<dim3(N1 / 64, N1 / 64), 256, 0, stream>>>(
        f1, f2, u1, N1, N2, c1, c2, nullptr, nullptr);
    k_correct_smooth<true><<<dim3(N0 / 64, N0 / 64), 256, 0, stream>>>(
        f0, u1, u0, N0, N1, c0, 1.0f, pT, pF);
    k_final<<<1, 256, 0, stream>>>(pT, pF, NB, res);
}

// Round 5
// 131.185 us; speedup vs baseline: 1.6672x; 1.6672x over previous
//
#include <hip/hip_runtime.h>

#define N0 4096
#define N1 2048
#define N2 1024

// lane i gets lane i-1's value (within 16-lane DPP row); row-lane 0 -> 0 (overridden)
__device__ __forceinline__ float dpp_from_left(float x) {
    return __int_as_float(__builtin_amdgcn_update_dpp(0, __float_as_int(x), 0x111, 0xf, 0xf, false));
}
// lane i gets lane i+1's value; row-lane 15 -> 0 (overridden)
__device__ __forceinline__ float dpp_from_right(float x) {
    return __int_as_float(__builtin_amdgcn_update_dpp(0, __float_as_int(x), 0x101, 0xf, 0xf, false));
}

// ============ restrict: fc = restrict(f + 0.2*L(f)) ============
// 256 threads = (tx 0..15, ty 0..15); each thread: 2x2 coarse outputs = 4x4 fine quad.
// Block: 32x32 coarse = 64x64 fine tile.
__global__ __launch_bounds__(256, 4) void k_res_restrict(const float* __restrict__ f,
                                                         float* __restrict__ fc,
                                                         int n, int nc) {
    __shared__ __align__(16) float sf[66][72];   // rows fy0-1..fy0+64, cols fx0-4..fx0+67
    const int tid = threadIdx.x;
    const int tx = tid & 15, ty = tid >> 4;
    const int fy0 = blockIdx.y * 64, fx0 = blockIdx.x * 64;
    const bool edge = (blockIdx.x == 0) | (blockIdx.y == 0) |
                      (blockIdx.x == gridDim.x - 1) | (blockIdx.y == gridDim.y - 1);
    if (!edge) {
        for (int idx = tid; idx < 66 * 18; idx += 256) {
            int r = idx / 18, c = idx - r * 18;
            *(float4*)&sf[r][4 * c] =
                *(const float4*)(f + (size_t)(fy0 - 1 + r) * n + (fx0 - 4 + 4 * c));
        }
    } else {
        for (int idx = tid; idx < 66 * 72; idx += 256) {
            int r = idx / 72, c = idx - r * 72;
            int gy = fy0 - 1 + r, gx = fx0 - 4 + c;
            float v = 0.0f;
            if ((unsigned)gy < (unsigned)n && (unsigned)gx < (unsigned)n)
                v = f[(size_t)gy * n + gx];
            sf[r][c] = v;
        }
    }
    __syncthreads();

    // f window: fine rows 4ty-1..4ty+4 (sf rows 4ty..4ty+5), cols 4tx-1..4tx+4
    float fa[6][6];
    #pragma unroll
    for (int rr = 0; rr < 6; ++rr) {
        float4 o = *(const float4*)&sf[4 * ty + rr][4 * tx + 4];
        fa[rr][1] = o.x; fa[rr][2] = o.y; fa[rr][3] = o.z; fa[rr][4] = o.w;
        fa[rr][0] = dpp_from_left(o.w);
        fa[rr][5] = dpp_from_right(o.x);
    }
    if (tx == 0) {
        #pragma unroll
        for (int rr = 0; rr < 6; ++rr) fa[rr][0] = sf[4 * ty + rr][3];
    }
    if (tx == 15) {
        #pragma unroll
        for (int rr = 0; rr < 6; ++rr) fa[rr][5] = sf[4 * ty + rr][68];
    }

    float rv[4][4];
    #pragma unroll
    for (int i = 0; i < 4; ++i) {
        #pragma unroll
        for (int j = 0; j < 4; ++j) {
            float c = fa[1 + i][1 + j];
            rv[i][j] = c + 0.2f * (fa[i][1 + j] + fa[2 + i][1 + j] +
                                   fa[1 + i][j] + fa[1 + i][2 + j] - 4.0f * c);
        }
    }
    if (edge) {
        #pragma unroll
        for (int i = 0; i < 4; ++i) {
            #pragma unroll
            for (int j = 0; j < 4; ++j) {
                int gy = fy0 + 4 * ty + i, gx = fx0 + 4 * tx + j;
                if (gy == 0 || gy == n - 1 || gx == 0 || gx == n - 1)
                    rv[i][j] = fa[1 + i][1 + j];
            }
        }
    }
    #pragma unroll
    for (int da = 0; da < 2; ++da) {
        float2 o;
        o.x = 0.25f * (rv[2*da][0] + rv[2*da][1] + rv[2*da+1][0] + rv[2*da+1][1]);
        o.y = 0.25f * (rv[2*da][2] + rv[2*da][3] + rv[2*da+1][2] + rv[2*da+1][3]);
        *(float2*)(fc + (size_t)(fy0 / 2 + 2 * ty + da) * nc + (fx0 / 2 + 2 * tx)) = o;
    }
}

// ====== fused: u = jacobi(cf*f + cs*prolong(uc), f), optional fused residual ======
// Block: 64(x) x 32(y) outputs, 256 threads = (tx 0..15, ty 0..15), each 4 cols x 2 rows.
// sf : f, rows by0-2..by0+33 (36), cols bx0-4..bx0+67 (72)
// suc: cs*uc, rows by0/2-2..by0/2+17 (20), cols bx0/2-2..bx0/2+33 (36; stride 37)
// su : u (+1 halo), rows by0-1..by0+32 (34), col idx = gx-(bx0-4)
template <bool RESID>
__global__ __launch_bounds__(256, 4) void k_correct_smooth(
        const float* __restrict__ f, const float* __restrict__ uc,
        float* __restrict__ u, int n, int m, float cf, float cs,
        double* __restrict__ pT, double* __restrict__ pF) {
    __shared__ __align__(16) float sf[36][72];
    __shared__ float suc[20][37];
    __shared__ __align__(16) float su[RESID ? 34 : 1][72];
    const int tid = threadIdx.x;
    const int tx = tid & 15, ty = tid >> 4;
    const int by0 = blockIdx.y * 32, bx0 = blockIdx.x * 64;
    const bool edge = (blockIdx.x == 0) | (blockIdx.y == 0) |
                      (blockIdx.x == gridDim.x - 1) | (blockIdx.y == gridDim.y - 1);

    // ---- staging ----
    if (!edge) {
        for (int idx = tid; idx < 36 * 18; idx += 256) {
            int r = idx / 18, c = idx - r * 18;
            *(float4*)&sf[r][4 * c] =
                *(const float4*)(f + (size_t)(by0 - 2 + r) * n + (bx0 - 4 + 4 * c));
        }
        for (int idx = tid; idx < 20 * 18; idx += 256) {
            int r = idx / 18, c2 = idx - r * 18;
            float2 vv = *(const float2*)(uc + (size_t)(by0 / 2 - 2 + r) * m + (bx0 / 2 - 2 + 2 * c2));
            suc[r][2 * c2]     = cs * vv.x;
            suc[r][2 * c2 + 1] = cs * vv.y;
        }
    } else {
        for (int idx = tid; idx < 36 * 72; idx += 256) {
            int r = idx / 72, c = idx - r * 72;
            int gy = by0 - 2 + r, gx = bx0 - 4 + c;
            float fv = 0.0f;
            if ((unsigned)gy < (unsigned)n && (unsigned)gx < (unsigned)n)
                fv = f[(size_t)gy * n + gx];
            sf[r][c] = fv;
        }
        for (int idx = tid; idx < 20 * 36; idx += 256) {
            int r = idx / 36, c = idx - r * 36;
            int gy = by0 / 2 - 2 + r, gx = bx0 / 2 - 2 + c;
            float v = 0.0f;
            if ((unsigned)gy < (unsigned)m && (unsigned)gx < (unsigned)m)
                v = cs * uc[(size_t)gy * m + gx];
            suc[r][c] = v;
        }
    }
    __syncthreads();

    // ---- f window (rows by0+2ty-1..+2, cols bx0+4tx-1..+4) via float4 + DPP sides ----
    float fr[4][6];
    {
        float4 f4[4];
        #pragma unroll
        for (int r = 0; r < 4; ++r) f4[r] = *(const float4*)&sf[2 * ty + 1 + r][4 * tx + 4];
        #pragma unroll
        for (int r = 0; r < 4; ++r) {
            fr[r][1] = f4[r].x; fr[r][2] = f4[r].y; fr[r][3] = f4[r].z; fr[r][4] = f4[r].w;
            fr[r][0] = dpp_from_left(f4[r].w);
            fr[r][5] = dpp_from_right(f4[r].x);
        }
        if (tx == 0) {
            #pragma unroll
            for (int r = 0; r < 4; ++r) fr[r][0] = sf[2 * ty + 1 + r][3];
        }
        if (tx == 15) {
            #pragma unroll
            for (int r = 0; r < 4; ++r) fr[r][5] = sf[2 * ty + 1 + r][68];
        }
    }

    // ---- coarse window + horizontal interp ----
    float cu[3][4];
    #pragma unroll
    for (int i = 0; i < 3; ++i)
        #pragma unroll
        for (int j = 0; j < 4; ++j) cu[i][j] = suc[ty + 1 + i][2 * tx + 1 + j];
    float h[3][6];
    #pragma unroll
    for (int i = 0; i < 3; ++i) {
        h[i][0] = 1.5f * cu[i][0] + 0.5f * cu[i][1];
        h[i][1] = 0.5f * cu[i][0] + 1.5f * cu[i][1];
        h[i][2] = 1.5f * cu[i][1] + 0.5f * cu[i][2];
        h[i][3] = 0.5f * cu[i][1] + 1.5f * cu[i][2];
        h[i][4] = 1.5f * cu[i][2] + 0.5f * cu[i][3];
        h[i][5] = 0.5f * cu[i][2] + 1.5f * cu[i][3];
    }
    // ---- v = cf*f + prolong (rows fy = by0+2ty-1..+2) ----
    float v[4][6];
    #pragma unroll
    for (int j = 0; j < 6; ++j) {
        v[0][j] = 1.5f * h[0][j] + 0.5f * h[1][j] + cf * fr[0][j];
        v[1][j] = 0.5f * h[0][j] + 1.5f * h[1][j] + cf * fr[1][j];
        v[2][j] = 1.5f * h[1][j] + 0.5f * h[2][j] + cf * fr[2][j];
        v[3][j] = 0.5f * h[1][j] + 1.5f * h[2][j] + cf * fr[3][j];
    }
    if (edge) {
        #pragma unroll
        for (int r = 0; r < 4; ++r)
            #pragma unroll
            for (int j = 0; j < 6; ++j) {
                int gy = by0 + 2 * ty - 1 + r, gx = bx0 + 4 * tx - 1 + j;
                if (gy == 0 || gy == n - 1 || gx == 0 || gx == n - 1) v[r][j] = cf * fr[r][j];
            }
    }
    // ---- u on own 2x4 ----
    float u2[2][4];
    #pragma unroll
    for (int rr = 0; rr < 2; ++rr)
        #pragma unroll
        for (int cc = 0; cc < 4; ++cc) {
            float vc = v[1 + rr][1 + cc];
            u2[rr][cc] = vc + cf * fr[1 + rr][1 + cc]
                       + 0.2f * (v[rr][1 + cc] + v[2 + rr][1 + cc] +
                                 v[1 + rr][cc] + v[1 + rr][2 + cc] - 4.0f * vc);
        }
    if (edge) {
        #pragma unroll
        for (int rr = 0; rr < 2; ++rr)
            #pragma unroll
            for (int cc = 0; cc < 4; ++cc) {
                int gy = by0 + 2 * ty + rr, gx = bx0 + 4 * tx + cc;
                if (gy == 0 || gy == n - 1 || gx == 0 || gx == n - 1)
                    u2[rr][cc] = v[1 + rr][1 + cc] + cf * fr[1 + rr][1 + cc];
            }
    }
    // ---- global store ----
    #pragma unroll
    for (int rr = 0; rr < 2; ++rr) {
        *(float4*)(u + (size_t)(by0 + 2 * ty + rr) * n + (bx0 + 4 * tx)) =
            make_float4(u2[rr][0], u2[rr][1], u2[rr][2], u2[rr][3]);
    }

    if (RESID) {
        float uL[2] = {0.0f, 0.0f}, uR[2] = {0.0f, 0.0f};
        // own u into su
        #pragma unroll
        for (int rr = 0; rr < 2; ++rr)
            *(float4*)&su[2 * ty + 1 + rr][4 * tx + 4] =
                make_float4(u2[rr][0], u2[rr][1], u2[rr][2], u2[rr][3]);
        // --- top halo u row (gy = by0-1), computed by ty==0 ---
        if (ty == 0) {
            float4 fm = *(const float4*)&sf[0][4 * tx + 4];
            float c0 = suc[0][2 * tx + 1], c1 = suc[0][2 * tx + 2],
                  c2 = suc[0][2 * tx + 3], c3 = suc[0][2 * tx + 4];
            float hm[4] = { 0.5f * c0 + 1.5f * c1, 1.5f * c1 + 0.5f * c2,
                            0.5f * c1 + 1.5f * c2, 1.5f * c2 + 0.5f * c3 };
            float fmv[4] = { fm.x, fm.y, fm.z, fm.w };
            float vm[4];
            #pragma unroll
            for (int cc = 0; cc < 4; ++cc) vm[cc] = 0.5f * hm[cc] + 1.5f * h[0][1 + cc] + cf * fmv[cc];
            if (edge) {
                #pragma unroll
                for (int cc = 0; cc < 4; ++cc) {
                    int gx = bx0 + 4 * tx + cc;
                    if (gx == 0 || gx == n - 1) vm[cc] = cf * fmv[cc];
                }
            }
            float uH[4];
            #pragma unroll
            for (int cc = 0; cc < 4; ++cc) {
                float vc = v[0][1 + cc];
                uH[cc] = vc + cf * fr[0][1 + cc]
                       + 0.2f * (vm[cc] + v[1][1 + cc] + v[0][cc] + v[0][2 + cc] - 4.0f * vc);
            }
            if (edge) {
                #pragma unroll
                for (int cc = 0; cc < 4; ++cc) {
                    int gx = bx0 + 4 * tx + cc;
                    if (gx == 0 || gx == n - 1) uH[cc] = v[0][1 + cc] + cf * fr[0][1 + cc];
                }
            }
            *(float4*)&su[0][4 * tx + 4] = make_float4(uH[0], uH[1], uH[2], uH[3]);
        }
        // --- bottom halo u row (gy = by0+32), computed by ty==15 ---
        if (ty == 15) {
            float4 fp = *(const float4*)&sf[35][4 * tx + 4];
            float c0 = suc[19][2 * tx + 1], c1 = suc[19][2 * tx + 2],
                  c2 = suc[19][2 * tx + 3], c3 = suc[19][2 * tx + 4];
            float hp[4] = { 0.5f * c0 + 1.5f * c1, 1.5f * c1 + 0.5f * c2,
                            0.5f * c1 + 1.5f * c2, 1.5f * c2 + 0.5f * c3 };
            float fpv[4] = { fp.x, fp.y, fp.z, fp.w };
            float vp[4];
            #pragma unroll
            for (int cc = 0; cc < 4; ++cc) vp[cc] = 1.5f * h[2][1 + cc] + 0.5f * hp[cc] + cf * fpv[cc];
            if (edge) {
                #pragma unroll
                for (int cc = 0; cc < 4; ++cc) {
                    int gx = bx0 + 4 * tx + cc;
                    if (gx == 0 || gx == n - 1) vp[cc] = cf * fpv[cc];
                }
            }
            float uH[4];
            #pragma unroll
            for (int cc = 0; cc < 4; ++cc) {
                float vc = v[3][1 + cc];
                uH[cc] = vc + cf * fr[3][1 + cc]
                       + 0.2f * (v[2][1 + cc] + vp[cc] + v[3][cc] + v[3][2 + cc] - 4.0f * vc);
            }
            if (edge) {
                #pragma unroll
                for (int cc = 0; cc < 4; ++cc) {
                    int gx = bx0 + 4 * tx + cc;
                    if (gx == 0 || gx == n - 1) uH[cc] = v[3][1 + cc] + cf * fr[3][1 + cc];
                }
            }
            *(float4*)&su[33][4 * tx + 4] = make_float4(uH[0], uH[1], uH[2], uH[3]);
        }
        // --- left halo u col (gx = bx0-1), computed by tx==0 ---
        if (tx == 0) {
            float cL0 = suc[ty + 1][0], cL1 = suc[ty + 2][0], cL2 = suc[ty + 3][0];
            float hL0 = 0.5f * cL0 + 1.5f * cu[0][0];
            float hL1 = 0.5f * cL1 + 1.5f * cu[1][0];
            float hL2 = 0.5f * cL2 + 1.5f * cu[2][0];
            float fL1 = sf[2 * ty + 2][2], fL2 = sf[2 * ty + 3][2];
            float vL[2] = { 0.5f * hL0 + 1.5f * hL1 + cf * fL1,
                            1.5f * hL1 + 0.5f * hL2 + cf * fL2 };
            if (edge) {
                #pragma unroll
                for (int k = 0; k < 2; ++k) {
                    int gy = by0 + 2 * ty + k;
                    if (gy == 0 || gy == n - 1) vL[k] = cf * ((k == 0) ? fL1 : fL2);
                }
            }
            #pragma unroll
            for (int rr = 0; rr < 2; ++rr) {
                float vc = v[1 + rr][0];
                uL[rr] = vc + cf * fr[1 + rr][0]
                       + 0.2f * (v[rr][0] + v[2 + rr][0] + vL[rr] + v[1 + rr][1] - 4.0f * vc);
                if (edge) {
                    int gy = by0 + 2 * ty + rr;
                    if (gy == 0 || gy == n - 1) uL[rr] = vc + cf * fr[1 + rr][0];
                }
                su[2 * ty + 1 + rr][3] = uL[rr];
            }
        }
        // --- right halo u col (gx = bx0+64), computed by tx==15 ---
        if (tx == 15) {
            float cR0 = suc[ty + 1][35], cR1 = suc[ty + 2][35], cR2 = suc[ty + 3][35];
            float hR0 = 1.5f * cu[0][3] + 0.5f * cR0;
            float hR1 = 1.5f * cu[1][3] + 0.5f * cR1;
            float hR2 = 1.5f * cu[2][3] + 0.5f * cR2;
            float fR1 = sf[2 * ty + 2][69], fR2 = sf[2 * ty + 3][69];
            float vR[2] = { 0.5f * hR0 + 1.5f * hR1 + cf * fR1,
                            1.5f * hR1 + 0.5f * hR2 + cf * fR2 };
            if (edge) {
                #pragma unroll
                for (int k = 0; k < 2; ++k) {
                    int gy = by0 + 2 * ty + k;
                    if (gy == 0 || gy == n - 1) vR[k] = cf * ((k == 0) ? fR1 : fR2);
                }
            }
            #pragma unroll
            for (int rr = 0; rr < 2; ++rr) {
                float vc = v[1 + rr][5];
                uR[rr] = vc + cf * fr[1 + rr][5]
                       + 0.2f * (v[rr][5] + v[2 + rr][5] + v[1 + rr][4] + vR[rr] - 4.0f * vc);
                if (edge) {
                    int gy = by0 + 2 * ty + rr;
                    if (gy == 0 || gy == n - 1) uR[rr] = vc + cf * fr[1 + rr][5];
                }
                su[2 * ty + 1 + rr][68] = uR[rr];
            }
        }
        __syncthreads();
        // --- residual: |f - n^2 L(u)| using regs + su halo + DPP sides ---
        float4 tv = *(const float4*)&su[2 * ty][4 * tx + 4];
        float4 bv = *(const float4*)&su[2 * ty + 3][4 * tx + 4];
        float ta[4] = { tv.x, tv.y, tv.z, tv.w };
        float ba[4] = { bv.x, bv.y, bv.z, bv.w };
        float lft[2], rgt[2];
        lft[0] = dpp_from_left(u2[0][3]);  lft[1] = dpp_from_left(u2[1][3]);
        rgt[0] = dpp_from_right(u2[0][0]); rgt[1] = dpp_from_right(u2[1][0]);
        if (tx == 0)  { lft[0] = uL[0]; lft[1] = uL[1]; }
        if (tx == 15) { rgt[0] = uR[0]; rgt[1] = uR[1]; }
        const float n2 = (float)n * (float)n;
        float accT = 0.0f, accF = 0.0f;
        #pragma unroll
        for (int rr = 0; rr < 2; ++rr) {
            #pragma unroll
            for (int cc = 0; cc < 4; ++cc) {
                float up = (rr == 0) ? ta[cc] : u2[0][cc];
                float dn = (rr == 1) ? ba[cc] : u2[1][cc];
                float lf = (cc == 0) ? lft[rr] : u2[rr][cc - 1];
                float rt = (cc == 3) ? rgt[rr] : u2[rr][cc + 1];
                float uu = u2[rr][cc];
                float fij = fr[1 + rr][1 + cc];
                float L = up + dn + lf + rt - 4.0f * uu;
                float t = fabsf(fij - n2 * L);
                if (edge) {
                    int gy = by0 + 2 * ty + rr, gx = bx0 + 4 * tx + cc;
                    if (gy == 0 || gy == n - 1 || gx == 0 || gx == n - 1) t = fabsf(fij);
                }
                accT += t;
                accF += fabsf(fij);
            }
        }
        // --- block reduction (f64) reusing sf ---
        double* sT = (double*)&sf[0][0];
        double* sF = sT + 256;
        sT[tid] = (double)accT; sF[tid] = (double)accF;
        __syncthreads();
        for (int s = 128; s > 0; s >>= 1) {
            if (tid < s) { sT[tid] += sT[tid + s]; sF[tid] += sF[tid + s]; }
            __syncthreads();
        }
        if (tid == 0) {
            int bid = blockIdx.y * gridDim.x + blockIdx.x;
            pT[bid] = sT[0];
            pF[bid] = sF[0];
        }
    }
}

__global__ void k_final(const double* __restrict__ pT, const double* __restrict__ pF,
                        int nb, float* __restrict__ out_res) {
    __shared__ double sT[256], sF[256];
    double tT = 0.0, tF = 0.0;
    for (int i = threadIdx.x; i < nb; i += 256) { tT += pT[i]; tF += pF[i]; }
    sT[threadIdx.x] = tT; sF[threadIdx.x] = tF;
    __syncthreads();
    for (int s = 128; s > 0; s >>= 1) {
        if (threadIdx.x < s) { sT[threadIdx.x] += sT[threadIdx.x + s]; sF[threadIdx.x] += sF[threadIdx.x + s]; }
        __syncthreads();
    }
    if (threadIdx.x == 0) *out_res = (float)(sT[0] / sF[0]);
}

extern "C" void kernel_launch(void* const* d_in, const int* in_sizes, int n_in,
                              void* d_out, int out_size, void* d_ws, size_t ws_size,
                              hipStream_t stream) {
    const float* f0 = (const float*)d_in[0];
    float* u0  = (float*)d_out;
    float* res = u0 + (size_t)N0 * N0;

    char* ws = (char*)d_ws;
    float* f1 = (float*)ws;                                            // N1*N1
    float* u1 = (float*)(ws + (size_t)N1 * N1 * 4);                    // N1*N1
    float* f2 = (float*)(ws + (size_t)2 * N1 * N1 * 4);                // N2*N2
    double* pT = (double*)(ws + (size_t)2 * N1 * N1 * 4 + (size_t)N2 * N2 * 4);
    const int NB = (N0 / 64) * (N0 / 32);                              // 8192
    double* pF = pT + NB;

    const float c0 = -0.2f / ((float)N0 * (float)N0);
    const float c1 = -0.2f / ((float)N1 * (float)N1);
    const float c2 = -0.2f / ((float)N2 * (float)N2);

    k_res_restrict<<<dim3(N1 / 32, N1 / 32), 256, 0, stream>>>(f0, f1, N0, N1);
    k_res_restrict<<<dim3(N2 / 32, N2 / 32), 256, 0, stream>>>(f1, f2, N1, N2);
    k_correct_smooth<false><<<dim3(N1 / 64, N1 / 32), 256, 0, stream>>>(
        f1, f2, u1, N1, N2, c1, c2, nullptr, nullptr);
    k_correct_smooth<true><<<dim3(N0 / 64, N0 / 32), 256, 0, stream>>>(
        f0, u1, u0, N0, N1, c0, 1.0f, pT, pF);
    k_final<<<1, 256, 0, stream>>>(pT, pF, NB, res);
}

// Round 6
// 119.409 us; speedup vs baseline: 1.8316x; 1.0986x over previous
//
#include <hip/hip_runtime.h>

#define N0 4096
#define N1 2048
#define N2 1024

// lane i gets lane i-1's value (within 16-lane DPP row); row-lane 0 -> 0 (overridden)
__device__ __forceinline__ float dpp_from_left(float x) {
    return __int_as_float(__builtin_amdgcn_update_dpp(0, __float_as_int(x), 0x111, 0xf, 0xf, false));
}
// lane i gets lane i+1's value; row-lane 15 -> 0 (overridden)
__device__ __forceinline__ float dpp_from_right(float x) {
    return __int_as_float(__builtin_amdgcn_update_dpp(0, __float_as_int(x), 0x101, 0xf, 0xf, false));
}

// ============ restrict: fc = restrict(f + 0.2*L(f)) — zero LDS ============
// 256 threads = (tx 0..15, ty 0..15); each thread: 2x2 coarse outputs = 4x4 fine quad.
// Block: 64x64 fine tile = 32x32 coarse outputs.
__global__ __launch_bounds__(256, 4) void k_res_restrict(const float* __restrict__ f,
                                                         float* __restrict__ fc,
                                                         int n, int nc) {
    const int tid = threadIdx.x;
    const int tx = tid & 15, ty = tid >> 4;
    const int fy0 = blockIdx.y * 64, fx0 = blockIdx.x * 64;
    const bool edge = (blockIdx.x == 0) | (blockIdx.y == 0) |
                      (blockIdx.x == gridDim.x - 1) | (blockIdx.y == gridDim.y - 1);

    // fine window rows fy0+4ty-1 .. +4, cols fx0+4tx-1 .. +4 (clamped rows; DPP sides)
    float fa[6][6];
    #pragma unroll
    for (int rr = 0; rr < 6; ++rr) {
        int gy = fy0 + 4 * ty - 1 + rr;
        gy = max(0, min(n - 1, gy));
        const float* rowp = f + (size_t)gy * n;
        float4 o = *(const float4*)(rowp + fx0 + 4 * tx);
        fa[rr][1] = o.x; fa[rr][2] = o.y; fa[rr][3] = o.z; fa[rr][4] = o.w;
        fa[rr][0] = dpp_from_left(o.w);
        fa[rr][5] = dpp_from_right(o.x);
        if (tx == 0)  fa[rr][0] = rowp[max(0, fx0 - 1)];
        if (tx == 15) fa[rr][5] = rowp[min(n - 1, fx0 + 64)];
    }

    float rv[4][4];
    #pragma unroll
    for (int i = 0; i < 4; ++i) {
        #pragma unroll
        for (int j = 0; j < 4; ++j) {
            float c = fa[1 + i][1 + j];
            rv[i][j] = c + 0.2f * (fa[i][1 + j] + fa[2 + i][1 + j] +
                                   fa[1 + i][j] + fa[1 + i][2 + j] - 4.0f * c);
        }
    }
    if (edge) {
        #pragma unroll
        for (int i = 0; i < 4; ++i)
            #pragma unroll
            for (int j = 0; j < 4; ++j) {
                int gy = fy0 + 4 * ty + i, gx = fx0 + 4 * tx + j;
                if (gy == 0 || gy == n - 1 || gx == 0 || gx == n - 1)
                    rv[i][j] = fa[1 + i][1 + j];
            }
    }
    #pragma unroll
    for (int da = 0; da < 2; ++da) {
        float2 o;
        o.x = 0.25f * (rv[2*da][0] + rv[2*da][1] + rv[2*da+1][0] + rv[2*da+1][1]);
        o.y = 0.25f * (rv[2*da][2] + rv[2*da][3] + rv[2*da+1][2] + rv[2*da+1][3]);
        *(float2*)(fc + (size_t)(fy0 / 2 + 2 * ty + da) * nc + (fx0 / 2 + 2 * tx)) = o;
    }
}

// ====== fused: u = jacobi(cf*f + cs*prolong(uc), f), optional fused residual ======
// Block: 64(x) x 32(y) outputs, 256 threads = (tx,ty), each 4 cols x 2 rows.
// Direct global loads (clamped) + DPP; LDS only for u halo exchange (RESID).
template <bool RESID>
__global__ __launch_bounds__(256, 4) void k_correct_smooth(
        const float* __restrict__ f, const float* __restrict__ uc,
        float* __restrict__ u, int n, int m, float cf, float cs,
        double* __restrict__ pT, double* __restrict__ pF) {
    __shared__ __align__(16) float su[RESID ? 34 : 1][68];   // row = gy-(by0-1), col = gx-bx0
    __shared__ double sred[8];
    const int tid = threadIdx.x;
    const int tx = tid & 15, ty = tid >> 4;
    const int by0 = blockIdx.y * 32, bx0 = blockIdx.x * 64;
    const int B = bx0 >> 1;
    const bool edge = (blockIdx.x == 0) | (blockIdx.y == 0) |
                      (blockIdx.x == gridDim.x - 1) | (blockIdx.y == gridDim.y - 1);

    // ---- f window: rows by0+2ty-1..+2, cols bx0+4tx-1..+4 ----
    float fr[4][6];
    #pragma unroll
    for (int r = 0; r < 4; ++r) {
        int gy = by0 + 2 * ty - 1 + r;
        gy = max(0, min(n - 1, gy));
        const float* rowp = f + (size_t)gy * n;
        float4 o = *(const float4*)(rowp + bx0 + 4 * tx);
        fr[r][1] = o.x; fr[r][2] = o.y; fr[r][3] = o.z; fr[r][4] = o.w;
        fr[r][0] = dpp_from_left(o.w);
        fr[r][5] = dpp_from_right(o.x);
        if (tx == 0)  fr[r][0] = rowp[max(0, bx0 - 1)];
        if (tx == 15) fr[r][5] = rowp[min(n - 1, bx0 + 64)];
    }

    // ---- coarse window: rows by0/2-1+ty..+2, cols B+2tx-1..+2 (pre-scaled by cs) ----
    float cu[3][4];
    #pragma unroll
    for (int i = 0; i < 3; ++i) {
        int gy = by0 / 2 - 1 + ty + i;
        gy = max(0, min(m - 1, gy));
        const float* rowp = uc + (size_t)gy * m;
        float2 o = *(const float2*)(rowp + B + 2 * tx);
        float l  = dpp_from_left(o.y);
        float rg = dpp_from_right(o.x);
        if (tx == 0)  l  = rowp[max(0, B - 1)];
        if (tx == 15) rg = rowp[min(m - 1, B + 32)];
        cu[i][0] = cs * l; cu[i][1] = cs * o.x; cu[i][2] = cs * o.y; cu[i][3] = cs * rg;
    }

    // ---- horizontal interp ----
    float h[3][6];
    #pragma unroll
    for (int i = 0; i < 3; ++i) {
        h[i][0] = 1.5f * cu[i][0] + 0.5f * cu[i][1];
        h[i][1] = 0.5f * cu[i][0] + 1.5f * cu[i][1];
        h[i][2] = 1.5f * cu[i][1] + 0.5f * cu[i][2];
        h[i][3] = 0.5f * cu[i][1] + 1.5f * cu[i][2];
        h[i][4] = 1.5f * cu[i][2] + 0.5f * cu[i][3];
        h[i][5] = 0.5f * cu[i][2] + 1.5f * cu[i][3];
    }
    // ---- v = cf*f + prolong on rows by0+2ty-1..+2, cols bx0+4tx-1..+4 ----
    float v[4][6];
    #pragma unroll
    for (int j = 0; j < 6; ++j) {
        v[0][j] = 1.5f * h[0][j] + 0.5f * h[1][j] + cf * fr[0][j];
        v[1][j] = 0.5f * h[0][j] + 1.5f * h[1][j] + cf * fr[1][j];
        v[2][j] = 1.5f * h[1][j] + 0.5f * h[2][j] + cf * fr[2][j];
        v[3][j] = 0.5f * h[1][j] + 1.5f * h[2][j] + cf * fr[3][j];
    }
    if (edge) {
        #pragma unroll
        for (int r = 0; r < 4; ++r)
            #pragma unroll
            for (int j = 0; j < 6; ++j) {
                int gy = by0 + 2 * ty - 1 + r, gx = bx0 + 4 * tx - 1 + j;
                if (gy == 0 || gy == n - 1 || gx == 0 || gx == n - 1) v[r][j] = cf * fr[r][j];
            }
    }
    // ---- u on own 2x4 ----
    float u2[2][4];
    #pragma unroll
    for (int rr = 0; rr < 2; ++rr)
        #pragma unroll
        for (int cc = 0; cc < 4; ++cc) {
            float vc = v[1 + rr][1 + cc];
            u2[rr][cc] = vc + cf * fr[1 + rr][1 + cc]
                       + 0.2f * (v[rr][1 + cc] + v[2 + rr][1 + cc] +
                                 v[1 + rr][cc] + v[1 + rr][2 + cc] - 4.0f * vc);
        }
    if (edge) {
        #pragma unroll
        for (int rr = 0; rr < 2; ++rr)
            #pragma unroll
            for (int cc = 0; cc < 4; ++cc) {
                int gy = by0 + 2 * ty + rr, gx = bx0 + 4 * tx + cc;
                if (gy == 0 || gy == n - 1 || gx == 0 || gx == n - 1)
                    u2[rr][cc] = v[1 + rr][1 + cc] + cf * fr[1 + rr][1 + cc];
            }
    }
    // ---- global store ----
    #pragma unroll
    for (int rr = 0; rr < 2; ++rr)
        *(float4*)(u + (size_t)(by0 + 2 * ty + rr) * n + (bx0 + 4 * tx)) =
            make_float4(u2[rr][0], u2[rr][1], u2[rr][2], u2[rr][3]);

    if (RESID) {
        float uHt[4], uHb[4], uL[2] = {0.f, 0.f}, uR[2] = {0.f, 0.f};
        // --- top halo u row (gy = by0-1), ty==0 lanes (full DPP row active) ---
        if (ty == 0) {
            const float* rowp = f + (size_t)max(0, by0 - 2) * n;
            float4 fm4 = *(const float4*)(rowp + bx0 + 4 * tx);
            const float* crow = uc + (size_t)max(0, by0 / 2 - 2) * m;
            float2 o = *(const float2*)(crow + B + 2 * tx);
            float l  = dpp_from_left(o.y);
            float rg = dpp_from_right(o.x);
            if (tx == 0)  l  = crow[max(0, B - 1)];
            if (tx == 15) rg = crow[min(m - 1, B + 32)];
            l *= cs; rg *= cs;
            float ox = cs * o.x, oy = cs * o.y;
            float hm[4] = { 0.5f * l + 1.5f * ox, 1.5f * ox + 0.5f * oy,
                            0.5f * ox + 1.5f * oy, 1.5f * oy + 0.5f * rg };
            float fmv[4] = { fm4.x, fm4.y, fm4.z, fm4.w };
            float vm[4];
            #pragma unroll
            for (int cc = 0; cc < 4; ++cc) vm[cc] = 0.5f * hm[cc] + 1.5f * h[0][1 + cc] + cf * fmv[cc];
            if (edge) {
                #pragma unroll
                for (int cc = 0; cc < 4; ++cc) {
                    int gx = bx0 + 4 * tx + cc;
                    if (gx == 0 || gx == n - 1) vm[cc] = cf * fmv[cc];
                }
            }
            #pragma unroll
            for (int cc = 0; cc < 4; ++cc) {
                float vc = v[0][1 + cc];
                uHt[cc] = vc + cf * fr[0][1 + cc]
                        + 0.2f * (vm[cc] + v[1][1 + cc] + v[0][cc] + v[0][2 + cc] - 4.0f * vc);
            }
            if (edge) {
                #pragma unroll
                for (int cc = 0; cc < 4; ++cc) {
                    int gx = bx0 + 4 * tx + cc;
                    if (gx == 0 || gx == n - 1) uHt[cc] = v[0][1 + cc] + cf * fr[0][1 + cc];
                }
            }
        }
        // --- bottom halo u row (gy = by0+32), ty==15 lanes ---
        if (ty == 15) {
            const float* rowp = f + (size_t)min(n - 1, by0 + 33) * n;
            float4 fp4 = *(const float4*)(rowp + bx0 + 4 * tx);
            const float* crow = uc + (size_t)min(m - 1, by0 / 2 + 17) * m;
            float2 o = *(const float2*)(crow + B + 2 * tx);
            float l  = dpp_from_left(o.y);
            float rg = dpp_from_right(o.x);
            if (tx == 0)  l  = crow[max(0, B - 1)];
            if (tx == 15) rg = crow[min(m - 1, B + 32)];
            l *= cs; rg *= cs;
            float ox = cs * o.x, oy = cs * o.y;
            float hp[4] = { 0.5f * l + 1.5f * ox, 1.5f * ox + 0.5f * oy,
                            0.5f * ox + 1.5f * oy, 1.5f * oy + 0.5f * rg };
            float fpv[4] = { fp4.x, fp4.y, fp4.z, fp4.w };
            float vp[4];
            #pragma unroll
            for (int cc = 0; cc < 4; ++cc) vp[cc] = 1.5f * h[2][1 + cc] + 0.5f * hp[cc] + cf * fpv[cc];
            if (edge) {
                #pragma unroll
                for (int cc = 0; cc < 4; ++cc) {
                    int gx = bx0 + 4 * tx + cc;
                    if (gx == 0 || gx == n - 1) vp[cc] = cf * fpv[cc];
                }
            }
            #pragma unroll
            for (int cc = 0; cc < 4; ++cc) {
                float vc = v[3][1 + cc];
                uHb[cc] = vc + cf * fr[3][1 + cc]
                        + 0.2f * (v[2][1 + cc] + vp[cc] + v[3][cc] + v[3][2 + cc] - 4.0f * vc);
            }
            if (edge) {
                #pragma unroll
                for (int cc = 0; cc < 4; ++cc) {
                    int gx = bx0 + 4 * tx + cc;
                    if (gx == 0 || gx == n - 1) uHb[cc] = v[3][1 + cc] + cf * fr[3][1 + cc];
                }
            }
        }
        // --- left halo u col (gx = bx0-1), tx==0 (scalar loads, no DPP) ---
        if (tx == 0) {
            float cL[3], fL[2];
            #pragma unroll
            for (int i = 0; i < 3; ++i) {
                int gy = by0 / 2 - 1 + ty + i;
                gy = max(0, min(m - 1, gy));
                cL[i] = uc[(size_t)gy * m + max(0, B - 2)];
            }
            #pragma unroll
            for (int k = 0; k < 2; ++k)
                fL[k] = f[(size_t)(by0 + 2 * ty + k) * n + max(0, bx0 - 2)];
            float hL[3];
            #pragma unroll
            for (int i = 0; i < 3; ++i) hL[i] = 0.5f * cs * cL[i] + 1.5f * cu[i][0];
            float vL[2] = { 0.5f * hL[0] + 1.5f * hL[1] + cf * fL[0],
                            1.5f * hL[1] + 0.5f * hL[2] + cf * fL[1] };
            if (edge) {
                #pragma unroll
                for (int k = 0; k < 2; ++k) {
                    int gy = by0 + 2 * ty + k;
                    if (gy == 0 || gy == n - 1 || bx0 - 2 == 0) vL[k] = cf * fL[k];
                }
            }
            #pragma unroll
            for (int rr = 0; rr < 2; ++rr) {
                float vc = v[1 + rr][0];
                uL[rr] = vc + cf * fr[1 + rr][0]
                       + 0.2f * (v[rr][0] + v[2 + rr][0] + vL[rr] + v[1 + rr][1] - 4.0f * vc);
                if (edge) {
                    int gy = by0 + 2 * ty + rr;
                    if (gy == 0 || gy == n - 1) uL[rr] = vc + cf * fr[1 + rr][0];
                }
            }
        }
        // --- right halo u col (gx = bx0+64), tx==15 ---
        if (tx == 15) {
            float cR[3], fR[2];
            #pragma unroll
            for (int i = 0; i < 3; ++i) {
                int gy = by0 / 2 - 1 + ty + i;
                gy = max(0, min(m - 1, gy));
                cR[i] = uc[(size_t)gy * m + min(m - 1, B + 33)];
            }
            #pragma unroll
            for (int k = 0; k < 2; ++k)
                fR[k] = f[(size_t)(by0 + 2 * ty + k) * n + min(n - 1, bx0 + 65)];
            float hR[3];
            #pragma unroll
            for (int i = 0; i < 3; ++i) hR[i] = 1.5f * cu[i][3] + 0.5f * cs * cR[i];
            float vR[2] = { 0.5f * hR[0] + 1.5f * hR[1] + cf * fR[0],
                            1.5f * hR[1] + 0.5f * hR[2] + cf * fR[1] };
            if (edge) {
                #pragma unroll
                for (int k = 0; k < 2; ++k) {
                    int gy = by0 + 2 * ty + k;
                    if (gy == 0 || gy == n - 1 || bx0 + 65 == n - 1) vR[k] = cf * fR[k];
                }
            }
            #pragma unroll
            for (int rr = 0; rr < 2; ++rr) {
                float vc = v[1 + rr][5];
                uR[rr] = vc + cf * fr[1 + rr][5]
                       + 0.2f * (v[rr][5] + v[2 + rr][5] + v[1 + rr][4] + vR[rr] - 4.0f * vc);
                if (edge) {
                    int gy = by0 + 2 * ty + rr;
                    if (gy == 0 || gy == n - 1) uR[rr] = vc + cf * fr[1 + rr][5];
                }
            }
        }
        // --- u exchange via LDS ---
        #pragma unroll
        for (int rr = 0; rr < 2; ++rr)
            *(float4*)&su[2 * ty + 1 + rr][4 * tx] =
                make_float4(u2[rr][0], u2[rr][1], u2[rr][2], u2[rr][3]);
        if (ty == 0)  *(float4*)&su[0][4 * tx]  = make_float4(uHt[0], uHt[1], uHt[2], uHt[3]);
        if (ty == 15) *(float4*)&su[33][4 * tx] = make_float4(uHb[0], uHb[1], uHb[2], uHb[3]);
        __syncthreads();
        float4 tv = *(const float4*)&su[2 * ty][4 * tx];
        float4 bv = *(const float4*)&su[2 * ty + 3][4 * tx];
        float ta[4] = { tv.x, tv.y, tv.z, tv.w };
        float ba[4] = { bv.x, bv.y, bv.z, bv.w };
        float lft[2], rgt[2];
        lft[0] = dpp_from_left(u2[0][3]);  lft[1] = dpp_from_left(u2[1][3]);
        rgt[0] = dpp_from_right(u2[0][0]); rgt[1] = dpp_from_right(u2[1][0]);
        if (tx == 0)  { lft[0] = uL[0]; lft[1] = uL[1]; }
        if (tx == 15) { rgt[0] = uR[0]; rgt[1] = uR[1]; }
        const float n2 = (float)n * (float)n;
        float accT = 0.0f, accF = 0.0f;
        #pragma unroll
        for (int rr = 0; rr < 2; ++rr)
            #pragma unroll
            for (int cc = 0; cc < 4; ++cc) {
                float up = (rr == 0) ? ta[cc] : u2[0][cc];
                float dn = (rr == 1) ? ba[cc] : u2[1][cc];
                float lf = (cc == 0) ? lft[rr] : u2[rr][cc - 1];
                float rt = (cc == 3) ? rgt[rr] : u2[rr][cc + 1];
                float uu = u2[rr][cc];
                float fij = fr[1 + rr][1 + cc];
                float L = up + dn + lf + rt - 4.0f * uu;
                float t = fabsf(fij - n2 * L);
                if (edge) {
                    int gy = by0 + 2 * ty + rr, gx = bx0 + 4 * tx + cc;
                    if (gy == 0 || gy == n - 1 || gx == 0 || gx == n - 1) t = fabsf(fij);
                }
                accT += t;
                accF += fabsf(fij);
            }
        // --- reduction: wave shuffle then 4-wave combine ---
        double vT = (double)accT, vF = (double)accF;
        #pragma unroll
        for (int off = 32; off > 0; off >>= 1) {
            vT += __shfl_down(vT, off);
            vF += __shfl_down(vF, off);
        }
        int wid = tid >> 6;
        if ((tid & 63) == 0) { sred[wid] = vT; sred[wid + 4] = vF; }
        __syncthreads();
        if (tid == 0) {
            int bid = blockIdx.y * gridDim.x + blockIdx.x;
            pT[bid] = sred[0] + sred[1] + sred[2] + sred[3];
            pF[bid] = sred[4] + sred[5] + sred[6] + sred[7];
        }
    }
}

__global__ void k_final(const double* __restrict__ pT, const double* __restrict__ pF,
                        int nb, float* __restrict__ out_res) {
    __shared__ double sT[256], sF[256];
    double tT = 0.0, tF = 0.0;
    for (int i = threadIdx.x; i < nb; i += 256) { tT += pT[i]; tF += pF[i]; }
    sT[threadIdx.x] = tT; sF[threadIdx.x] = tF;
    __syncthreads();
    for (int s = 128; s > 0; s >>= 1) {
        if (threadIdx.x < s) { sT[threadIdx.x] += sT[threadIdx.x + s]; sF[threadIdx.x] += sF[threadIdx.x + s]; }
        __syncthreads();
    }
    if (threadIdx.x == 0) *out_res = (float)(sT[0] / sF[0]);
}

extern "C" void kernel_launch(void* const* d_in, const int* in_sizes, int n_in,
                              void* d_out, int out_size, void* d_ws, size_t ws_size,
                              hipStream_t stream) {
    const float* f0 = (const float*)d_in[0];
    float* u0  = (float*)d_out;
    float* res = u0 + (size_t)N0 * N0;

    char* ws = (char*)d_ws;
    float* f1 = (float*)ws;                                            // N1*N1
    float* u1 = (float*)(ws + (size_t)N1 * N1 * 4);                    // N1*N1
    float* f2 = (float*)(ws + (size_t)2 * N1 * N1 * 4);                // N2*N2
    double* pT = (double*)(ws + (size_t)2 * N1 * N1 * 4 + (size_t)N2 * N2 * 4);
    const int NB = (N0 / 64) * (N0 / 32);                              // 8192
    double* pF = pT + NB;

    const float c0 = -0.2f / ((float)N0 * (float)N0);
    const float c1 = -0.2f / ((float)N1 * (float)N1);
    const float c2 = -0.2f / ((float)N2 * (float)N2);

    k_res_restrict<<<dim3(N1 / 32, N1 / 32), 256, 0, stream>>>(f0, f1, N0, N1);
    k_res_restrict<<<dim3(N2 / 32, N2 / 32), 256, 0, stream>>>(f1, f2, N1, N2);
    k_correct_smooth<false><<<dim3(N1 / 64, N1 / 32), 256, 0, stream>>>(
        f1, f2, u1, N1, N2, c1, c2, nullptr, nullptr);
    k_correct_smooth<true><<<dim3(N0 / 64, N0 / 32), 256, 0, stream>>>(
        f0, u1, u0, N0, N1, c0, 1.0f, pT, pF);
    k_final<<<1, 256, 0, stream>>>(pT, pF, NB, res);
}